// Round 6
// baseline (113.914 us; speedup 1.0000x reference)
//
#include <hip/hip_runtime.h>
#include <math.h>
#include <stdint.h>

#define HH 512
#define WW 512
#define BB 64
#define NP 13860
#define WPR 16                       // 32-bit words per image row
#define IMG_WORDS (BB * HH * WPR)    // 2 MB bit-image for all batches

struct GaussW { float g[9]; };

__device__ __forceinline__ int reflect_idx(int i) {
    if (i < 0) i = -i;
    if (i > 511) i = 1022 - i;
    return i;
}

// ----------------------------------------------------------------- zero ----
// Custom fill: rocclr's graph memset node ran at 18 GB/s (~120 us for 2 MB).
__global__ __launch_bounds__(256)
void zero_kernel(uint4* __restrict__ p) {
    p[blockIdx.x * 256 + threadIdx.x] = make_uint4(0u, 0u, 0u, 0u);
}

// ---------------------------------------------------------------- splat ----
// One thread = one (point, batch).
__global__ __launch_bounds__(256)
void splat_kernel(const float* __restrict__ V,
                  const float* __restrict__ P,
                  const float* __restrict__ pts,
                  unsigned int* __restrict__ gbm) {
    __shared__ float VP[4][4];
    const int b = blockIdx.y;
    const int t = threadIdx.x;
    if (t < 16) {
        const int i = t >> 2, k = t & 3;
        const float* Pb = P + b * 16;
        const float* Vb = V + b * 16;
        float a = __fmul_rn(Pb[i*4+0], Vb[0*4+k]);
        a = __fmaf_rn(Pb[i*4+1], Vb[1*4+k], a);
        a = __fmaf_rn(Pb[i*4+2], Vb[2*4+k], a);
        a = __fmaf_rn(Pb[i*4+3], Vb[3*4+k], a);
        VP[i][k] = a;
    }
    __syncthreads();
    const int n = blockIdx.x * 256 + t;
    if (n >= NP) return;
    const float4 p = ((const float4*)pts)[n];
    float tp0, tp1, tp3;
    {
        float a = __fmul_rn(p.x, VP[0][0]);
        a = __fmaf_rn(p.y, VP[0][1], a);
        a = __fmaf_rn(p.z, VP[0][2], a);
        a = __fmaf_rn(p.w, VP[0][3], a);
        tp0 = a;
    }
    {
        float a = __fmul_rn(p.x, VP[1][0]);
        a = __fmaf_rn(p.y, VP[1][1], a);
        a = __fmaf_rn(p.z, VP[1][2], a);
        a = __fmaf_rn(p.w, VP[1][3], a);
        tp1 = a;
    }
    {
        float a = __fmul_rn(p.x, VP[3][0]);
        a = __fmaf_rn(p.y, VP[3][1], a);
        a = __fmaf_rn(p.z, VP[3][2], a);
        a = __fmaf_rn(p.w, VP[3][3], a);
        tp3 = a;
    }
    const float w = tp3;
    const float x = (w != 0.f) ? (tp0 / w) : tp0;
    const float y = (w != 0.f) ? (tp1 / w) : tp1;
    const float sxf = rintf(__fmul_rn(__fmul_rn(__fadd_rn(x, 1.f), 0.5f), 512.f));
    const float tmp = __fmul_rn(__fadd_rn(y, 1.f), 0.5f);
    const float syf = rintf(__fmul_rn(__fsub_rn(1.f, tmp), 512.f));
    int sx, sy;
    if (sxf >= 0.f && sxf < 512.f && syf >= 0.f && syf < 512.f) {
        sx = (int)sxf; sy = (int)syf;
    } else {
        sx = 511; sy = 511;   // JAX: flat=-1 wraps to last pixel, not dropped
    }
    atomicOr(&gbm[(b * HH + sy) * WPR + (sx >> 5)], 1u << (sx & 31));
}

// ------------------- tile kernel: dilate + blur + threshold + store --------
// One block = one (batch, 64x64 tile); bitmap halo loaded from global.
__global__ __launch_bounds__(256)
void tile_kernel(const unsigned int* __restrict__ gbm,
                 float* __restrict__ out, GaussW gw) {
    __shared__ unsigned int bm[80][4];   // splat bits, rows R0..R1, words W0..W0+3
    __shared__ unsigned int hd[80][4];   // horizontally dilated
    __shared__ unsigned int dl[72][4];   // fully dilated, rows RD0..RD1
    __shared__ float vs[64][73];         // vertical-blur result (72 padded cols)

    const int b  = blockIdx.z;
    const int x0 = blockIdx.x * 64;
    const int y0 = blockIdx.y * 64;
    const int tid = threadIdx.y * 16 + threadIdx.x;

    const int R0  = (y0 - 8 > 0) ? y0 - 8 : 0;
    const int R1  = (y0 + 71 < 511) ? y0 + 71 : 511;
    const int W0  = (x0 == 0) ? 0 : (x0 / 32 - 1);
    const int RD0 = (y0 - 4 > 0) ? y0 - 4 : 0;
    const int RD1 = (y0 + 67 < 511) ? y0 + 67 : 511;
    const int NR  = R1 - R0 + 1;

    // load bitmap halo (rows R0..R1, words W0..W0+3; OOB words -> 0)
    const unsigned int* gb = gbm + b * HH * WPR;
    for (int e = tid; e < 80 * 4; e += 256) {
        const int r = e >> 2, j = e & 3;
        unsigned int v = 0u;
        if (r < NR && W0 + j < WPR) v = gb[(R0 + r) * WPR + (W0 + j)];
        bm[r][j] = v;
    }
    __syncthreads();

    // horizontal dilation (+-4) via bit shifts
    for (int e = tid; e < NR * 4; e += 256) {
        const int r = e >> 2, j = e & 3;
        const unsigned int w  = bm[r][j];
        const unsigned int wl = (j > 0) ? bm[r][j-1] : 0u;
        const unsigned int wr = (j < 3) ? bm[r][j+1] : 0u;
        unsigned int h = w;
#pragma unroll
        for (int k = 1; k <= 4; ++k) {
            h |= (w << k) | (wl >> (32 - k));
            h |= (w >> k) | (wr << (32 - k));
        }
        hd[r][j] = h;
    }
    __syncthreads();

    // vertical dilation (+-4), clamped at image borders (== -inf SAME pad)
    const int ND = RD1 - RD0 + 1;
    for (int e = tid; e < ND * 4; e += 256) {
        const int r = RD0 + (e >> 2), j = e & 3;
        const int lo = (r - 4 > 0) ? r - 4 : 0;
        const int hi = (r + 4 < 511) ? r + 4 : 511;
        unsigned int acc = 0u;
        for (int rr = lo; rr <= hi; ++rr) acc |= hd[rr - R0][j];
        dl[r - RD0][j] = acc;
    }
    __syncthreads();

    // vertical 9-tap blur (reference conv order: H axis first), reflect pad
    for (int e = tid; e < 64 * 72; e += 256) {
        const int yy = e / 72;
        const int xc = e - yy * 72;
        const int col = reflect_idx(x0 + xc - 4);
        const int wj  = (col >> 5) - W0;
        const int bsh = col & 31;
        float acc = 0.f;
#pragma unroll
        for (int dy = 0; dy < 9; ++dy) {
            const int r = reflect_idx(y0 + yy + dy - 4);
            const float val = ((dl[r - RD0][wj] >> bsh) & 1u) ? 255.f : 0.f;
            acc = __fmaf_rn(gw.g[dy], val, acc);
        }
        vs[yy][xc] = acc;
    }
    __syncthreads();

    // horizontal 9-tap + threshold; 4 cols/thread -> float4 stores x3 channels
    const int c0 = threadIdx.x * 4;
#pragma unroll
    for (int k = 0; k < 4; ++k) {
        const int yy = threadIdx.y + 16 * k;
        float4 mq;
        float* mp = (float*)&mq;
#pragma unroll
        for (int q = 0; q < 4; ++q) {
            float acc = 0.f;
#pragma unroll
            for (int dx = 0; dx < 9; ++dx)
                acc = __fmaf_rn(gw.g[dx], vs[yy][c0 + q + dx], acc);
            mp[q] = (rintf(acc) > 100.f) ? 1.f : 0.f;
        }
        const int yq = y0 + yy, xq = x0 + c0;
        float* o = out + ((size_t)(b * 3) * HH + yq) * WW + xq;
        *(float4*)(o)                       = mq;
        *(float4*)(o + (size_t)HH * WW)     = mq;
        *(float4*)(o + (size_t)2 * HH * WW) = mq;
    }
}

// ---------------------------------------------------------------- launch ---
extern "C" void kernel_launch(void* const* d_in, const int* in_sizes, int n_in,
                              void* d_out, int out_size, void* d_ws, size_t ws_size,
                              hipStream_t stream) {
    const float* V   = (const float*)d_in[0];
    const float* P   = (const float*)d_in[1];
    const float* pts = (const float*)d_in[2];
    float* out = (float*)d_out;
    unsigned int* gbm = (unsigned int*)d_ws;   // 2 MB bit-image

    // Gaussian weights, replicating numpy f64 computation incl. pairwise sum
    const double sigma = 0.3 * ((9 - 1) * 0.5 - 1.0) + 0.8;
    double gd[9];
    for (int i = 0; i < 9; ++i) {
        const double t = ((double)i - 4.0) / sigma;
        gd[i] = exp(-0.5 * (t * t));
    }
    double s = ((gd[0] + gd[1]) + (gd[2] + gd[3])) + ((gd[4] + gd[5]) + (gd[6] + gd[7]));
    s += gd[8];
    GaussW gw;
    for (int i = 0; i < 9; ++i) gw.g[i] = (float)(gd[i] / s);

    zero_kernel<<<IMG_WORDS / 4 / 256, 256, 0, stream>>>((uint4*)gbm);
    splat_kernel<<<dim3((NP + 255) / 256, BB), 256, 0, stream>>>(V, P, pts, gbm);
    tile_kernel<<<dim3(8, 8, BB), dim3(16, 16), 0, stream>>>(gbm, out, gw);
}

// Round 7
// 84.408 us; speedup vs baseline: 1.3496x; 1.3496x over previous
//
#include <hip/hip_runtime.h>
#include <math.h>
#include <stdint.h>

#define HH 512
#define WW 512
#define BB 64
#define NP 13860
#define WPR 16                       // 32-bit words per image row
#define IMG_WORDS (BB * HH * WPR)    // 2 MB bit-image for all batches

struct GaussW { float g[9]; };

__device__ __forceinline__ int reflect_idx(int i) {
    if (i < 0) i = -i;
    if (i > 511) i = 1022 - i;
    return i;
}

// ----------------------------------------------------------------- zero ----
__global__ __launch_bounds__(256)
void zero_kernel(uint4* __restrict__ p) {
    p[blockIdx.x * 256 + threadIdx.x] = make_uint4(0u, 0u, 0u, 0u);
}

// ---------------------------------------------------------------- splat ----
// One thread = one (point, batch). Identical fp semantics to passing r4-r6.
__global__ __launch_bounds__(256)
void splat_kernel(const float* __restrict__ V,
                  const float* __restrict__ P,
                  const float* __restrict__ pts,
                  unsigned int* __restrict__ gbm) {
    __shared__ float VP[4][4];
    const int b = blockIdx.y;
    const int t = threadIdx.x;
    if (t < 16) {
        const int i = t >> 2, k = t & 3;
        const float* Pb = P + b * 16;
        const float* Vb = V + b * 16;
        float a = __fmul_rn(Pb[i*4+0], Vb[0*4+k]);
        a = __fmaf_rn(Pb[i*4+1], Vb[1*4+k], a);
        a = __fmaf_rn(Pb[i*4+2], Vb[2*4+k], a);
        a = __fmaf_rn(Pb[i*4+3], Vb[3*4+k], a);
        VP[i][k] = a;
    }
    __syncthreads();
    const int n = blockIdx.x * 256 + t;
    if (n >= NP) return;
    const float4 p = ((const float4*)pts)[n];
    float tp0, tp1, tp3;
    {
        float a = __fmul_rn(p.x, VP[0][0]);
        a = __fmaf_rn(p.y, VP[0][1], a);
        a = __fmaf_rn(p.z, VP[0][2], a);
        a = __fmaf_rn(p.w, VP[0][3], a);
        tp0 = a;
    }
    {
        float a = __fmul_rn(p.x, VP[1][0]);
        a = __fmaf_rn(p.y, VP[1][1], a);
        a = __fmaf_rn(p.z, VP[1][2], a);
        a = __fmaf_rn(p.w, VP[1][3], a);
        tp1 = a;
    }
    {
        float a = __fmul_rn(p.x, VP[3][0]);
        a = __fmaf_rn(p.y, VP[3][1], a);
        a = __fmaf_rn(p.z, VP[3][2], a);
        a = __fmaf_rn(p.w, VP[3][3], a);
        tp3 = a;
    }
    const float w = tp3;
    const float x = (w != 0.f) ? (tp0 / w) : tp0;
    const float y = (w != 0.f) ? (tp1 / w) : tp1;
    const float sxf = rintf(__fmul_rn(__fmul_rn(__fadd_rn(x, 1.f), 0.5f), 512.f));
    const float tmp = __fmul_rn(__fadd_rn(y, 1.f), 0.5f);
    const float syf = rintf(__fmul_rn(__fsub_rn(1.f, tmp), 512.f));
    int sx, sy;
    if (sxf >= 0.f && sxf < 512.f && syf >= 0.f && syf < 512.f) {
        sx = (int)sxf; sy = (int)syf;
    } else {
        sx = 511; sy = 511;   // JAX: flat=-1 wraps to last pixel, not dropped
    }
    atomicOr(&gbm[(b * HH + sy) * WPR + (sx >> 5)], 1u << (sx & 31));
}

// ------------------- tile kernel: dilate + blur + threshold + store --------
// One block = one (batch, 64x64 tile). Vertical blur via 512-entry LUT
// (bit-identical fma chain); blur patch held in registers per thread.
__global__ __launch_bounds__(256)
void tile_kernel(const unsigned int* __restrict__ gbm,
                 float* __restrict__ out, GaussW gw) {
    __shared__ unsigned int bm[80][4];   // splat bits, rows R0..R1, words W0..W0+3
    __shared__ unsigned int hd[80][4];   // horizontally dilated
    __shared__ unsigned int dl[72][4];   // fully dilated, rows RD0..RD1
    __shared__ float lut[512];           // vertical-blur LUT over 9-bit patterns

    const int b  = blockIdx.z;
    const int x0 = blockIdx.x * 64;
    const int y0 = blockIdx.y * 64;
    const int tx = threadIdx.x;          // 0..15 -> 4-col group
    const int ty = threadIdx.y;          // 0..15 -> 4-row group
    const int tid = ty * 16 + tx;

    const int R0  = (y0 - 8 > 0) ? y0 - 8 : 0;
    const int R1  = (y0 + 71 < 511) ? y0 + 71 : 511;
    const int W0  = (x0 == 0) ? 0 : (x0 / 32 - 1);
    const int RD0 = (y0 - 4 > 0) ? y0 - 4 : 0;
    const int RD1 = (y0 + 67 < 511) ? y0 + 67 : 511;
    const int NR  = R1 - R0 + 1;

    // phase A: load bitmap halo + build vertical-blur LUT (exact fma chain)
    const unsigned int* gb = gbm + b * HH * WPR;
    for (int e = tid; e < 80 * 4; e += 256) {
        const int r = e >> 2, j = e & 3;
        unsigned int v = 0u;
        if (r < NR && W0 + j < WPR) v = gb[(R0 + r) * WPR + (W0 + j)];
        bm[r][j] = v;
    }
    for (int e = tid; e < 512; e += 256) {
        float acc = 0.f;
#pragma unroll
        for (int dy = 0; dy < 9; ++dy) {
            const float val = ((e >> dy) & 1) ? 255.f : 0.f;
            acc = __fmaf_rn(gw.g[dy], val, acc);
        }
        lut[e] = acc;
    }
    __syncthreads();

    // phase B1: horizontal dilation (+-4) via bit shifts
    for (int e = tid; e < NR * 4; e += 256) {
        const int r = e >> 2, j = e & 3;
        const unsigned int w  = bm[r][j];
        const unsigned int wl = (j > 0) ? bm[r][j-1] : 0u;
        const unsigned int wr = (j < 3) ? bm[r][j+1] : 0u;
        unsigned int h = w;
#pragma unroll
        for (int k = 1; k <= 4; ++k) {
            h |= (w << k) | (wl >> (32 - k));
            h |= (w >> k) | (wr << (32 - k));
        }
        hd[r][j] = h;
    }
    __syncthreads();

    // phase B2: vertical dilation (+-4), clamped at image borders
    const int ND = RD1 - RD0 + 1;
    for (int e = tid; e < ND * 4; e += 256) {
        const int r = RD0 + (e >> 2), j = e & 3;
        const int lo = (r - 4 > 0) ? r - 4 : 0;
        const int hi = (r + 4 < 511) ? r + 4 : 511;
        unsigned int acc = 0u;
        for (int rr = lo; rr <= hi; ++rr) acc |= hd[rr - R0][j];
        dl[r - RD0][j] = acc;
    }
    __syncthreads();

    // phase C: per-thread 4-row x 4-col patch, all in registers.
    // Need vs(y, c) for rows y = y0+4*ty+r (r 0..3), cols j 0..11
    // (absolute col = reflect(x0 + 4*tx - 4 + j)).
    const int c0 = 4 * tx;

    // 12 dl-row indices (rows y0+4*ty-4+k, k 0..11, reflected, rebased)
    int ridx[12];
#pragma unroll
    for (int k = 0; k < 12; ++k)
        ridx[k] = reflect_idx(y0 + 4 * ty - 4 + k) - RD0;

    // the 12 needed cols span at most 2 bitmap words (reflection folds
    // edge cols back into the same word)
    const int colA = reflect_idx(x0 + c0 - 4);
    const int colB = reflect_idx(x0 + c0 + 7);
    const int wA = (colA >> 5) - W0;
    const int wB = (colB >> 5) - W0;

    unsigned int w_lo[12], w_hi[12];
#pragma unroll
    for (int k = 0; k < 12; ++k) {
        w_lo[k] = dl[ridx[k]][wA];
        w_hi[k] = dl[ridx[k]][wB];
    }

    // per column: 12-bit vertical stripe -> 4 patterns -> LUT
    float vs[4][12];
#pragma unroll
    for (int j = 0; j < 12; ++j) {
        const int col = reflect_idx(x0 + c0 - 4 + j);
        const int sel = (col >> 5) - W0;   // wA or wB
        const int sh  = col & 31;
        unsigned int v12 = 0u;
#pragma unroll
        for (int k = 0; k < 12; ++k) {
            const unsigned int wk = (sel == wB) ? w_hi[k] : w_lo[k];
            v12 |= ((wk >> sh) & 1u) << k;
        }
#pragma unroll
        for (int r = 0; r < 4; ++r)
            vs[r][j] = lut[(v12 >> r) & 0x1FFu];
    }

    // phase D: horizontal 9-tap (ascending dx fma chain) + threshold + store
#pragma unroll
    for (int r = 0; r < 4; ++r) {
        float4 mq;
        float* mp = (float*)&mq;
#pragma unroll
        for (int q = 0; q < 4; ++q) {
            float acc = 0.f;
#pragma unroll
            for (int dx = 0; dx < 9; ++dx)
                acc = __fmaf_rn(gw.g[dx], vs[r][q + dx], acc);
            mp[q] = (rintf(acc) > 100.f) ? 1.f : 0.f;
        }
        const int yq = y0 + 4 * ty + r, xq = x0 + c0;
        float* o = out + ((size_t)(b * 3) * HH + yq) * WW + xq;
        *(float4*)(o)                       = mq;
        *(float4*)(o + (size_t)HH * WW)     = mq;
        *(float4*)(o + (size_t)2 * HH * WW) = mq;
    }
}

// ---------------------------------------------------------------- launch ---
extern "C" void kernel_launch(void* const* d_in, const int* in_sizes, int n_in,
                              void* d_out, int out_size, void* d_ws, size_t ws_size,
                              hipStream_t stream) {
    const float* V   = (const float*)d_in[0];
    const float* P   = (const float*)d_in[1];
    const float* pts = (const float*)d_in[2];
    float* out = (float*)d_out;
    unsigned int* gbm = (unsigned int*)d_ws;   // 2 MB bit-image

    // Gaussian weights, replicating numpy f64 computation incl. pairwise sum
    const double sigma = 0.3 * ((9 - 1) * 0.5 - 1.0) + 0.8;
    double gd[9];
    for (int i = 0; i < 9; ++i) {
        const double t = ((double)i - 4.0) / sigma;
        gd[i] = exp(-0.5 * (t * t));
    }
    double s = ((gd[0] + gd[1]) + (gd[2] + gd[3])) + ((gd[4] + gd[5]) + (gd[6] + gd[7]));
    s += gd[8];
    GaussW gw;
    for (int i = 0; i < 9; ++i) gw.g[i] = (float)(gd[i] / s);

    zero_kernel<<<IMG_WORDS / 4 / 256, 256, 0, stream>>>((uint4*)gbm);
    splat_kernel<<<dim3((NP + 255) / 256, BB), 256, 0, stream>>>(V, P, pts, gbm);
    tile_kernel<<<dim3(8, 8, BB), dim3(16, 16), 0, stream>>>(gbm, out, gw);
}